// Round 5
// baseline (123.569 us; speedup 1.0000x reference)
//
#include <hip/hip_runtime.h>
#include <hip/hip_bf16.h>
#include <stdint.h>

// ---------------------------------------------------------------------------
// MMD loss, N=4096 source + 4096 target rows, D=256, fp32 in, fp32 scalar out.
//
//   loss = (1/ns^2) * sum_ij s_i s_j K(i,j),  s_i = +1 (source) / -1 (target)
//   K(i,j) = sum_{k=0..4} exp(-l2_ij / (bw0 * 2^k)),  l2 = |xi|^2+|xj|^2-2<xi,xj>
//   bw0 = [2n*sum|x|^2 - 2*|colsum|^2] / (n^2-n) / 4      (closed form, no Gram)
//
// R5: multi-tile blocks. R2-R4 showed every single-tile structure plateaus at
//   ~360 TF with NO pipe saturated -> per-block ramp (cold load latency before
//   first MFMA) dominates because K=256 gives only 8 kk steps per tile.
//   R4's k3 has no barriers, so a block processing 4 tiles back-to-back lets
//   VMEM stay saturated across tile boundaries and overlaps tile t's exp
//   epilogue (VALU) with tile t+1's frag loads (VMEM). Consecutive triangular
//   t mostly share bi -> A frags stay L1-hot. One reduction+atomic per block.
// ---------------------------------------------------------------------------

#define NROW 8192
#define NS   4096
#define DD   256
#define NTB  64                     // 8192/128 row tiles (128x128 per tile)
#define NBLK (NTB*(NTB+1)/2)        // 2080 triangular tiles
#define TPB  4                      // tiles per block
#define GRID (NBLK/TPB)             // 520 blocks
#define K1B  128                    // k1 blocks (64 rows each)

typedef __bf16 bf16_t;
typedef __bf16 bf16x8 __attribute__((ext_vector_type(8)));
typedef float  f32x4  __attribute__((ext_vector_type(4)));
typedef float  f32x2  __attribute__((ext_vector_type(2)));

// ws byte offsets
#define OFF_CPAR 0                          // float[4]
#define OFF_SQ   1024                       // float[8192]
#define OFF_CS   (OFF_SQ + 8192*4)          // float[K1B*256]
#define OFF_SS   (OFF_CS + K1B*256*4)       // float[K1B]
#define OFF_TBF  (1<<18)                    // bf16[8192*256] = 4 MB, panel-frag

// --------------------------- k1: prep ---------------------------------------
// Panel-frag layout: panel p = row>>4 (4096 bf16 = 8192 B per panel).
// Slot (c, r) at elem offset p*4096 + (c*16 + r)*8 holds row (p*16+r),
// k in [c*8, c*8+8). A k3 wave frag load for (p, kk) is then the contiguous
// 1 KB at p*4096 + kk*512 + lane*8  (lane l: c = kk*4 + l>>4, r = l&15).
__global__ __launch_bounds__(256) void k1_prep(const float* __restrict__ src,
                                               const float* __restrict__ tgt,
                                               float* __restrict__ sq,
                                               float* __restrict__ cs_part,
                                               float* __restrict__ ss_part,
                                               bf16_t* __restrict__ tbf,
                                               float* __restrict__ out) {
  const int b = blockIdx.x, tid = threadIdx.x;
  const int w = tid >> 6, l = tid & 63;
  if (b == 0 && tid == 0) out[0] = 0.f;     // k3 accumulates here (stream order)
  const int lr = l >> 4;                    // row sub-index 0..3
  const int lc = l & 15;                    // chunk sub-index 0..15
  const int p  = b * 4 + w;                 // this wave's panel (16 rows)

  float cacc[2][8];
  #pragma unroll
  for (int a = 0; a < 2; ++a)
    #pragma unroll
    for (int j = 0; j < 8; ++j) cacc[a][j] = 0.f;
  float wss = 0.f;                          // only lanes with lc==0 accumulate

  for (int i = 0; i < 4; ++i) {
    const int row = p * 16 + i * 4 + lr;
    const float* rp = (row < NS) ? (src + (size_t)row * DD)
                                 : (tgt + (size_t)(row - NS) * DD);
    float rowsq = 0.f;
    #pragma unroll
    for (int a = 0; a < 2; ++a) {
      const int c = a * 16 + lc;            // k-chunk 0..31
      float4 v0 = *(const float4*)(rp + c * 8);
      float4 v1 = *(const float4*)(rp + c * 8 + 4);
      bf16x8 o;
      o[0]=(bf16_t)v0.x; o[1]=(bf16_t)v0.y; o[2]=(bf16_t)v0.z; o[3]=(bf16_t)v0.w;
      o[4]=(bf16_t)v1.x; o[5]=(bf16_t)v1.y; o[6]=(bf16_t)v1.z; o[7]=(bf16_t)v1.w;
      *(bf16x8*)(tbf + (size_t)p * 4096 + (c * 16 + i * 4 + lr) * 8) = o;
      cacc[a][0]+=v0.x; cacc[a][1]+=v0.y; cacc[a][2]+=v0.z; cacc[a][3]+=v0.w;
      cacc[a][4]+=v1.x; cacc[a][5]+=v1.y; cacc[a][6]+=v1.z; cacc[a][7]+=v1.w;
      float s2 = v0.x*v0.x+v0.y*v0.y+v0.z*v0.z+v0.w*v0.w
               + v1.x*v1.x+v1.y*v1.y+v1.z*v1.z+v1.w*v1.w;
      #pragma unroll
      for (int off = 1; off <= 8; off <<= 1) s2 += __shfl_xor(s2, off);
      rowsq += s2;                          // valid on lc==0 lanes
    }
    if (lc == 0) { sq[row] = rowsq; wss += rowsq; }
  }

  // column sums: lanes sharing lc hold the same columns -> reduce over lr
  #pragma unroll
  for (int a = 0; a < 2; ++a)
    #pragma unroll
    for (int j = 0; j < 8; ++j) {
      float v = cacc[a][j];
      v += __shfl_xor(v, 16);
      v += __shfl_xor(v, 32);
      cacc[a][j] = v;
    }
  __shared__ float cls[4][256];
  __shared__ float sls[4];
  if (lr == 0) {
    #pragma unroll
    for (int a = 0; a < 2; ++a)
      #pragma unroll
      for (int j = 0; j < 8; ++j)
        cls[w][(a * 16 + lc) * 8 + j] = cacc[a][j];
  }
  // wss lives on lanes 0,16,32,48 (zero elsewhere)
  wss += __shfl_xor(wss, 16);
  wss += __shfl_xor(wss, 32);
  if (l == 0) sls[w] = wss;
  __syncthreads();
  cs_part[b * 256 + tid] = cls[0][tid] + cls[1][tid] + cls[2][tid] + cls[3][tid];
  if (tid == 0) ss_part[b] = sls[0] + sls[1] + sls[2] + sls[3];
}

// --------------------------- k2: bandwidth -----------------------------------
__global__ __launch_bounds__(256) void k2_bw(const float* __restrict__ cs_part,
                                             const float* __restrict__ ss_part,
                                             float* __restrict__ cpar) {
  const int tid = threadIdx.x, w = tid >> 6, lane = tid & 63;
  float c = 0.f;
  for (int b = 0; b < K1B; ++b) c += cs_part[b * 256 + tid];
  double csq = (double)c * (double)c;
  double ssq = (tid < K1B) ? (double)ss_part[tid] : 0.0;
  #pragma unroll
  for (int off = 32; off >= 1; off >>= 1) {
    csq += __shfl_xor(csq, off);
    ssq += __shfl_xor(ssq, off);
  }
  __shared__ double rc[4], rs[4];
  if (lane == 0) { rc[w] = csq; rs[w] = ssq; }
  __syncthreads();
  if (tid == 0) {
    double C = rc[0] + rc[1] + rc[2] + rc[3];
    double S = rs[0] + rs[1] + rs[2] + rs[3];
    const double n = (double)NROW;
    double suml2 = 2.0 * n * S - 2.0 * C;
    double bw0 = suml2 / (n * n - n) / 4.0;   // / KERNEL_MUL^(KERNEL_NUM//2)
    // v = exp2(-l2 * cE) = exp(-l2/(16*bw0)); kernels = v+v^2+v^4+v^8+v^16
    cpar[0] = (float)(1.4426950408889634 / (16.0 * bw0));
  }
}

// --------------------------- k3: LDS-free multi-tile Gram + epilogue ---------
__global__ __launch_bounds__(256) void k3_mmd(const bf16_t* __restrict__ tbf,
                                              const float* __restrict__ sqg,
                                              const float* __restrict__ cpar,
                                              float* __restrict__ out) {
  __shared__ float red[4];

  const int tid = threadIdx.x;
  const int w = tid >> 6, l = tid & 63;
  const int mh = w >> 1, nh = w & 1;               // wave quadrant in 128x128
  const int m0 = mh * 64, n0 = nh * 64;

  const float cE = cpar[0];
  const f32x2 c2 = {2.0f * cE, 2.0f * cE};

  f32x2 gtot = {0.f, 0.f};                         // signed per-lane total

  for (int s = 0; s < TPB; ++s) {
    const int t = blockIdx.x * TPB + s;
    int bi = (int)((sqrtf(8.0f * (float)t + 1.0f) - 1.0f) * 0.5f);
    while ((bi + 1) * (bi + 2) / 2 <= t) ++bi;
    while (bi * (bi + 1) / 2 > t) --bi;
    const int bj = t - bi * (bi + 1) / 2;          // bj <= bi

    // frag-direct bases; frag (panel+mi, kk) is contiguous 1 KB at
    // base + mi*4096 + kk*512 (+ lane*8 folded in).
    const bf16_t* Abase = tbf + (size_t)(bi * 8 + mh * 4) * 4096 + l * 8;
    const bf16_t* Bbase = tbf + (size_t)(bj * 8 + nh * 4) * 4096 + l * 8;

    f32x4 acc[4][4] = {};
    #pragma unroll 2
    for (int kk = 0; kk < 8; ++kk) {               // K = 256 in chunks of 32
      bf16x8 af[4], bfr[4];
      #pragma unroll
      for (int mi = 0; mi < 4; ++mi)
        af[mi] = *(const bf16x8*)(Abase + mi * 4096 + kk * 512);
      #pragma unroll
      for (int ni = 0; ni < 4; ++ni)
        bfr[ni] = *(const bf16x8*)(Bbase + ni * 4096 + kk * 512);
      #pragma unroll
      for (int mi = 0; mi < 4; ++mi)
        #pragma unroll
        for (int ni = 0; ni < 4; ++ni)
          acc[mi][ni] = __builtin_amdgcn_mfma_f32_16x16x32_bf16(
              af[mi], bfr[ni], acc[mi][ni], 0, 0, 0);
    }

    // Fused epilogue: e = (2g - sqi - sqj)*cE; v = 2^e; K = v+v^2+v^4+v^8+v^16
    f32x2 bj2[4];
    #pragma unroll
    for (int ni = 0; ni < 4; ++ni) {
      const float b = sqg[bj * 128 + n0 + ni * 16 + (l & 15)] * cE;
      bj2[ni][0] = b; bj2[ni][1] = b;
    }
    f32x2 t2 = {0.f, 0.f};
    #pragma unroll
    for (int mi = 0; mi < 4; ++mi) {
      const int mbase = bi * 128 + m0 + mi * 16 + (l >> 4) * 4;
      f32x2 ai2[2];
      ai2[0][0] = sqg[mbase + 0] * cE; ai2[0][1] = sqg[mbase + 1] * cE;
      ai2[1][0] = sqg[mbase + 2] * cE; ai2[1][1] = sqg[mbase + 3] * cE;
      #pragma unroll
      for (int ni = 0; ni < 4; ++ni) {
        #pragma unroll
        for (int h = 0; h < 2; ++h) {
          f32x2 g; g[0] = acc[mi][ni][2*h]; g[1] = acc[mi][ni][2*h+1];
          f32x2 e = g * c2 - (ai2[h] + bj2[ni]);
          f32x2 v;
          v[0] = __builtin_amdgcn_exp2f(e[0]);
          v[1] = __builtin_amdgcn_exp2f(e[1]);
          f32x2 v2 = v * v, v4 = v2 * v2, v8 = v4 * v4, v16 = v8 * v8;
          t2 += ((v + v2) + (v4 + v8)) + v16;
        }
      }
    }
    const float sign = ((bi < NS / 128) == (bj < NS / 128)) ? 1.f : -1.f;
    const float wt   = (bi == bj) ? sign : 2.f * sign;
    gtot[0] = fmaf(t2[0], wt, gtot[0]);
    gtot[1] = fmaf(t2[1], wt, gtot[1]);
  }

  float tsum = gtot[0] + gtot[1];
  #pragma unroll
  for (int off = 32; off >= 1; off >>= 1) tsum += __shfl_xor(tsum, off);
  if (l == 0) red[w] = tsum;
  __syncthreads();
  if (tid == 0) {
    const float sblk = red[0] + red[1] + red[2] + red[3];
    // 1/NS^2 == 2^-24, exact
    atomicAdd(out, sblk * (1.0f / ((float)NS * (float)NS)));
  }
}

// --------------------------- launch ------------------------------------------
extern "C" void kernel_launch(void* const* d_in, const int* in_sizes, int n_in,
                              void* d_out, int out_size, void* d_ws, size_t ws_size,
                              hipStream_t stream) {
  const float* src = (const float*)d_in[0];
  const float* tgt = (const float*)d_in[1];
  char* ws = (char*)d_ws;
  float*  cpar = (float*)(ws + OFF_CPAR);
  float*  sq   = (float*)(ws + OFF_SQ);
  float*  csp  = (float*)(ws + OFF_CS);
  float*  ssp  = (float*)(ws + OFF_SS);
  bf16_t* tbf  = (bf16_t*)(ws + OFF_TBF);
  float*  out  = (float*)d_out;

  k1_prep<<<K1B, 256, 0, stream>>>(src, tgt, sq, csp, ssp, tbf, out);
  k2_bw  <<<1,   256, 0, stream>>>(csp, ssp, cpar);
  k3_mmd <<<GRID,256, 0, stream>>>(tbf, sq, cpar, out);
}

// Round 6
// 108.590 us; speedup vs baseline: 1.1379x; 1.1379x over previous
//
#include <hip/hip_runtime.h>
#include <hip/hip_bf16.h>
#include <stdint.h>

// ---------------------------------------------------------------------------
// MMD loss, N=4096 source + 4096 target rows, D=256, fp32 in, fp32 scalar out.
//
//   loss = (1/ns^2) * sum_ij s_i s_j K(i,j),  s_i = +1 (source) / -1 (target)
//   K(i,j) = sum_{k=0..4} exp(-l2_ij / (bw0 * 2^k)),  l2 = |xi|^2+|xj|^2-2<xi,xj>
//   bw0 = [2n*sum|x|^2 - 2*|colsum|^2] / (n^2-n) / 4      (closed form, no Gram)
//
// R6: register double-buffered K-loop. R2-R5 evidence: every macro structure
//   ties at 43-48us with no pipe >36% busy and VGPR=96-100 -- the compiler
//   never software-pipelined the frag loads, so every kk step exposes the
//   full L2 latency (load 8 frags -> vmcnt(0) -> 16 MFMA). Fix at source
//   level: two disjoint frag register sets; issue kk+1's 8 loads BEFORE
//   kk's MFMAs so the auto-waitcnt becomes vmcnt(8) and loads stay in
//   flight under compute. TPB=1 (R5's grid shrink regressed).
// ---------------------------------------------------------------------------

#define NROW 8192
#define NS   4096
#define DD   256
#define NTB  64                     // 8192/128 row tiles (128x128 per tile)
#define NBLK (NTB*(NTB+1)/2)        // 2080 triangular tiles
#define K1B  128                    // k1 blocks (64 rows each)

typedef __bf16 bf16_t;
typedef __bf16 bf16x8 __attribute__((ext_vector_type(8)));
typedef float  f32x4  __attribute__((ext_vector_type(4)));
typedef float  f32x2  __attribute__((ext_vector_type(2)));

// ws byte offsets
#define OFF_CPAR 0                          // float[4]
#define OFF_SQ   1024                       // float[8192]
#define OFF_CS   (OFF_SQ + 8192*4)          // float[K1B*256]
#define OFF_SS   (OFF_CS + K1B*256*4)       // float[K1B]
#define OFF_TBF  (1<<18)                    // bf16[8192*256] = 4 MB, panel-frag

// --------------------------- k1: prep ---------------------------------------
// Panel-frag layout: panel p = row>>4 (4096 bf16 = 8192 B per panel).
// Slot (c, r) at elem offset p*4096 + (c*16 + r)*8 holds row (p*16+r),
// k in [c*8, c*8+8). A k3 wave frag load for (p, kk) is then the contiguous
// 1 KB at p*4096 + kk*512 + lane*8  (lane l: c = kk*4 + l>>4, r = l&15).
__global__ __launch_bounds__(256) void k1_prep(const float* __restrict__ src,
                                               const float* __restrict__ tgt,
                                               float* __restrict__ sq,
                                               float* __restrict__ cs_part,
                                               float* __restrict__ ss_part,
                                               bf16_t* __restrict__ tbf,
                                               float* __restrict__ out) {
  const int b = blockIdx.x, tid = threadIdx.x;
  const int w = tid >> 6, l = tid & 63;
  if (b == 0 && tid == 0) out[0] = 0.f;     // k3 accumulates here (stream order)
  const int lr = l >> 4;                    // row sub-index 0..3
  const int lc = l & 15;                    // chunk sub-index 0..15
  const int p  = b * 4 + w;                 // this wave's panel (16 rows)

  float cacc[2][8];
  #pragma unroll
  for (int a = 0; a < 2; ++a)
    #pragma unroll
    for (int j = 0; j < 8; ++j) cacc[a][j] = 0.f;
  float wss = 0.f;                          // only lanes with lc==0 accumulate

  for (int i = 0; i < 4; ++i) {
    const int row = p * 16 + i * 4 + lr;
    const float* rp = (row < NS) ? (src + (size_t)row * DD)
                                 : (tgt + (size_t)(row - NS) * DD);
    float rowsq = 0.f;
    #pragma unroll
    for (int a = 0; a < 2; ++a) {
      const int c = a * 16 + lc;            // k-chunk 0..31
      float4 v0 = *(const float4*)(rp + c * 8);
      float4 v1 = *(const float4*)(rp + c * 8 + 4);
      bf16x8 o;
      o[0]=(bf16_t)v0.x; o[1]=(bf16_t)v0.y; o[2]=(bf16_t)v0.z; o[3]=(bf16_t)v0.w;
      o[4]=(bf16_t)v1.x; o[5]=(bf16_t)v1.y; o[6]=(bf16_t)v1.z; o[7]=(bf16_t)v1.w;
      *(bf16x8*)(tbf + (size_t)p * 4096 + (c * 16 + i * 4 + lr) * 8) = o;
      cacc[a][0]+=v0.x; cacc[a][1]+=v0.y; cacc[a][2]+=v0.z; cacc[a][3]+=v0.w;
      cacc[a][4]+=v1.x; cacc[a][5]+=v1.y; cacc[a][6]+=v1.z; cacc[a][7]+=v1.w;
      float s2 = v0.x*v0.x+v0.y*v0.y+v0.z*v0.z+v0.w*v0.w
               + v1.x*v1.x+v1.y*v1.y+v1.z*v1.z+v1.w*v1.w;
      #pragma unroll
      for (int off = 1; off <= 8; off <<= 1) s2 += __shfl_xor(s2, off);
      rowsq += s2;                          // valid on lc==0 lanes
    }
    if (lc == 0) { sq[row] = rowsq; wss += rowsq; }
  }

  // column sums: lanes sharing lc hold the same columns -> reduce over lr
  #pragma unroll
  for (int a = 0; a < 2; ++a)
    #pragma unroll
    for (int j = 0; j < 8; ++j) {
      float v = cacc[a][j];
      v += __shfl_xor(v, 16);
      v += __shfl_xor(v, 32);
      cacc[a][j] = v;
    }
  __shared__ float cls[4][256];
  __shared__ float sls[4];
  if (lr == 0) {
    #pragma unroll
    for (int a = 0; a < 2; ++a)
      #pragma unroll
      for (int j = 0; j < 8; ++j)
        cls[w][(a * 16 + lc) * 8 + j] = cacc[a][j];
  }
  // wss lives on lanes 0,16,32,48 (zero elsewhere)
  wss += __shfl_xor(wss, 16);
  wss += __shfl_xor(wss, 32);
  if (l == 0) sls[w] = wss;
  __syncthreads();
  cs_part[b * 256 + tid] = cls[0][tid] + cls[1][tid] + cls[2][tid] + cls[3][tid];
  if (tid == 0) ss_part[b] = sls[0] + sls[1] + sls[2] + sls[3];
}

// --------------------------- k2: bandwidth -----------------------------------
__global__ __launch_bounds__(256) void k2_bw(const float* __restrict__ cs_part,
                                             const float* __restrict__ ss_part,
                                             float* __restrict__ cpar) {
  const int tid = threadIdx.x, w = tid >> 6, lane = tid & 63;
  float c = 0.f;
  for (int b = 0; b < K1B; ++b) c += cs_part[b * 256 + tid];
  double csq = (double)c * (double)c;
  double ssq = (tid < K1B) ? (double)ss_part[tid] : 0.0;
  #pragma unroll
  for (int off = 32; off >= 1; off >>= 1) {
    csq += __shfl_xor(csq, off);
    ssq += __shfl_xor(ssq, off);
  }
  __shared__ double rc[4], rs[4];
  if (lane == 0) { rc[w] = csq; rs[w] = ssq; }
  __syncthreads();
  if (tid == 0) {
    double C = rc[0] + rc[1] + rc[2] + rc[3];
    double S = rs[0] + rs[1] + rs[2] + rs[3];
    const double n = (double)NROW;
    double suml2 = 2.0 * n * S - 2.0 * C;
    double bw0 = suml2 / (n * n - n) / 4.0;   // / KERNEL_MUL^(KERNEL_NUM//2)
    // v = exp2(-l2 * cE) = exp(-l2/(16*bw0)); kernels = v+v^2+v^4+v^8+v^16
    cpar[0] = (float)(1.4426950408889634 / (16.0 * bw0));
  }
}

// --------------------------- k3: LDS-free Gram, reg-dbuf K-loop --------------
__global__ __launch_bounds__(256) void k3_mmd(const bf16_t* __restrict__ tbf,
                                              const float* __restrict__ sqg,
                                              const float* __restrict__ cpar,
                                              float* __restrict__ out) {
  __shared__ float red[4];

  const int t = blockIdx.x;
  int bi = (int)((sqrtf(8.0f * (float)t + 1.0f) - 1.0f) * 0.5f);
  while ((bi + 1) * (bi + 2) / 2 <= t) ++bi;
  while (bi * (bi + 1) / 2 > t) --bi;
  const int bj = t - bi * (bi + 1) / 2;            // bj <= bi

  const int tid = threadIdx.x;
  const int w = tid >> 6, l = tid & 63;
  const int mh = w >> 1, nh = w & 1;               // wave quadrant in 128x128
  const int m0 = mh * 64, n0 = nh * 64;

  const float cE = cpar[0];

  // frag-direct bases; frag (panel+mi, kk) is the contiguous 1 KB at
  // base + mi*4096 + kk*512 (+ lane*8 folded into base).
  const bf16_t* Abase = tbf + (size_t)(bi * 8 + mh * 4) * 4096 + l * 8;
  const bf16_t* Bbase = tbf + (size_t)(bj * 8 + nh * 4) * 4096 + l * 8;

  f32x4 acc[4][4] = {};

  // 2-deep register double-buffer: fr[buf][0..3]=A frags, [4..7]=B frags.
  bf16x8 fr[2][8];
  #pragma unroll
  for (int mi = 0; mi < 4; ++mi)
    fr[0][mi] = *(const bf16x8*)(Abase + mi * 4096);
  #pragma unroll
  for (int ni = 0; ni < 4; ++ni)
    fr[0][4 + ni] = *(const bf16x8*)(Bbase + ni * 4096);

  #pragma unroll
  for (int kk = 0; kk < 8; ++kk) {                 // K = 256 in chunks of 32
    const int cur = kk & 1, nxt = cur ^ 1;
    if (kk < 7) {                                  // prefetch kk+1 first
      #pragma unroll
      for (int mi = 0; mi < 4; ++mi)
        fr[nxt][mi] = *(const bf16x8*)(Abase + mi * 4096 + (kk + 1) * 512);
      #pragma unroll
      for (int ni = 0; ni < 4; ++ni)
        fr[nxt][4 + ni] = *(const bf16x8*)(Bbase + ni * 4096 + (kk + 1) * 512);
    }
    #pragma unroll
    for (int mi = 0; mi < 4; ++mi)
      #pragma unroll
      for (int ni = 0; ni < 4; ++ni)
        acc[mi][ni] = __builtin_amdgcn_mfma_f32_16x16x32_bf16(
            fr[cur][mi], fr[cur][4 + ni], acc[mi][ni], 0, 0, 0);
  }

  // Fused epilogue, float2-packed (v_pk_*_f32):
  //   e = (2g - sqi - sqj)*cE; v = 2^e; K = v+v^2+v^4+v^8+v^16
  const f32x2 c2 = {2.0f * cE, 2.0f * cE};
  f32x2 bj2[4];
  #pragma unroll
  for (int ni = 0; ni < 4; ++ni) {
    const float b = sqg[bj * 128 + n0 + ni * 16 + (l & 15)] * cE;
    bj2[ni][0] = b; bj2[ni][1] = b;
  }

  f32x2 t2 = {0.f, 0.f};
  #pragma unroll
  for (int mi = 0; mi < 4; ++mi) {
    const int mbase = bi * 128 + m0 + mi * 16 + (l >> 4) * 4;
    f32x2 ai2[2];
    ai2[0][0] = sqg[mbase + 0] * cE; ai2[0][1] = sqg[mbase + 1] * cE;
    ai2[1][0] = sqg[mbase + 2] * cE; ai2[1][1] = sqg[mbase + 3] * cE;
    #pragma unroll
    for (int ni = 0; ni < 4; ++ni) {
      #pragma unroll
      for (int h = 0; h < 2; ++h) {
        f32x2 g; g[0] = acc[mi][ni][2*h]; g[1] = acc[mi][ni][2*h+1];
        f32x2 e = g * c2 - (ai2[h] + bj2[ni]);
        f32x2 v;
        v[0] = __builtin_amdgcn_exp2f(e[0]);
        v[1] = __builtin_amdgcn_exp2f(e[1]);
        f32x2 v2 = v * v, v4 = v2 * v2, v8 = v4 * v4, v16 = v8 * v8;
        t2 += ((v + v2) + (v4 + v8)) + v16;
      }
    }
  }
  float tsum = t2[0] + t2[1];
  #pragma unroll
  for (int off = 32; off >= 1; off >>= 1) tsum += __shfl_xor(tsum, off);
  if (l == 0) red[w] = tsum;
  __syncthreads();
  if (tid == 0) {
    const float s    = red[0] + red[1] + red[2] + red[3];
    const float sign = ((bi < NS / 128) == (bj < NS / 128)) ? 1.f : -1.f;
    const float wt   = (bi == bj) ? 1.f : 2.f;     // off-diag tiles counted twice
    // 1/NS^2 == 2^-24, exact
    atomicAdd(out, s * sign * wt * (1.0f / ((float)NS * (float)NS)));
  }
}

// --------------------------- launch ------------------------------------------
extern "C" void kernel_launch(void* const* d_in, const int* in_sizes, int n_in,
                              void* d_out, int out_size, void* d_ws, size_t ws_size,
                              hipStream_t stream) {
  const float* src = (const float*)d_in[0];
  const float* tgt = (const float*)d_in[1];
  char* ws = (char*)d_ws;
  float*  cpar = (float*)(ws + OFF_CPAR);
  float*  sq   = (float*)(ws + OFF_SQ);
  float*  csp  = (float*)(ws + OFF_CS);
  float*  ssp  = (float*)(ws + OFF_SS);
  bf16_t* tbf  = (bf16_t*)(ws + OFF_TBF);
  float*  out  = (float*)d_out;

  k1_prep<<<K1B, 256, 0, stream>>>(src, tgt, sq, csp, ssp, tbf, out);
  k2_bw  <<<1,   256, 0, stream>>>(csp, ssp, cpar);
  k3_mmd <<<NBLK,256, 0, stream>>>(tbf, sq, cpar, out);
}